// Round 7
// baseline (215.154 us; speedup 1.0000x reference)
//
#include <hip/hip_runtime.h>

#define NSTEPS 64

typedef __attribute__((ext_vector_type(4)))  float  float4_;   // 16x16 MFMA C/D
typedef __attribute__((ext_vector_type(2)))  __fp16 half2_;    // packed f16
typedef __attribute__((ext_vector_type(8)))  __fp16 half8_;    // f16 MFMA A/B operand

__device__ __forceinline__ half2_ relu_pk_f16(float a, float b) {
    half2_ h = __builtin_amdgcn_cvt_pkrtz(a, b);               // v_cvt_pkrtz_f16_f32
    return __builtin_elementwise_max(h, (half2_)(__fp16)0);    // v_pk_max_f16
}

// R21 (this round): 16x16x32 rewrite for TLP. R6 counters: VALU-bound at 62%
// saturation; 32-sample waves cap residency at 4096 waves = 4/SIMD. 16
// samples/wave -> 8192 waves -> up to 8/SIMD, at ~constant VALU/sample.
// 16x16x32 f16 layout (C/D HW-verified per guide m89; A/B by analogy with
// the session-verified 32x32 mapping):
//   A[m][k]: m=lane&15, k=(lane>>4)*8+j
//   B[k][n]: n=lane&15, k=(lane>>4)*8+j
//   C/D[row][col]: col=lane&15, row=(lane>>4)*4+reg
// sigma position permutation (p = output position, u = hidden unit):
//   sig(p) = ((p&15)>>2)*8 + (p&3) + (p<16 ? 0 : 4)
// Applied to layer1/layer2 OUTPUT order so each lane's D regs pack pairwise
// into the next layer's B-frag: lane quad has D*_0 regs = units quad*8+0..3,
// D*_1 regs = units quad*8+4..7 -> B k=quad*8+j exactly. 4 relu_pk/transition.
// Layer2: K=32 in ONE MFMA per 16-unit output half -> two INDEPENDENT MFMAs.
// Layer3: ONE MFMA, K=32; rows (m&3)<3 duplicate w3 (R5/R6-validated) so
// every quad's D3[0..2] = k0..k2 directly; b3 folded into C3.
// RK-fold (R6): A1 k-slots 0..2=W1,3=b1,4..6=ci*W1,7=0; B=(y,1,kprev,0);
// A k>=8 columns are ZERO so quads 1..3's B values are don't-cares.
__global__ __launch_bounds__(256, 6)
void ode_rk4_mfma(const float* __restrict__ x,
                  const float* __restrict__ samples,
                  const float* __restrict__ w1, const float* __restrict__ b1,
                  const float* __restrict__ w2, const float* __restrict__ b2,
                  const float* __restrict__ w3, const float* __restrict__ b3,
                  const float* __restrict__ w_out, const float* __restrict__ b_out,
                  float* __restrict__ out, int B)
{
    const int lane  = threadIdx.x & 63;
    const int w     = threadIdx.x >> 6;
    const int col16 = lane & 15;              // this lane's sample (mod 16)
    const int quad  = lane >> 4;              // 0..3 (k-group / row-group)

    const int rowBase = (blockIdx.x * 4 + w) * 16;
    const int row = rowBase + col16;          // sample row (4x redundant over quads)

    // sigma: output-position -> hidden-unit
    auto sig = [](int p) -> int {
        int q = (p & 15) >> 2, r = p & 3;
        return q * 8 + r + ((p < 16) ? 0 : 4);
    };

    // ---- scalars ----
    const float maxT = samples[7];
    const float dt   = maxT / 64.0f;
    const float dt2  = 0.5f * dt;
    const float dt6  = dt / 6.0f;

    // ---- persistent MFMA operands ----
    // Layer1 A variants (two 16-unit halves x two ci): lane m=col16 is the
    // hidden position; only quad 0 carries k=0..7 data, quads 1..3 zero.
    union F { half2_ h2[4]; half8_ h8; };
    F A1h[2], A1f[2];
#pragma unroll
    for (int H = 0; H < 2; ++H) {
        if (quad == 0) {
            int u = sig(16 * H + col16);
            float v0 = w1[0 * 32 + u], v1 = w1[1 * 32 + u], v2 = w1[2 * 32 + u];
            float bb = b1[u];
            A1h[H].h2[0] = (half2_){(__fp16)v0, (__fp16)v1};
            A1h[H].h2[1] = (half2_){(__fp16)v2, (__fp16)bb};
            A1h[H].h2[2] = (half2_){(__fp16)(dt2 * v0), (__fp16)(dt2 * v1)};
            A1h[H].h2[3] = (half2_){(__fp16)(dt2 * v2), (__fp16)0.0f};
            A1f[H].h2[0] = A1h[H].h2[0];
            A1f[H].h2[1] = A1h[H].h2[1];
            A1f[H].h2[2] = (half2_){(__fp16)(dt * v0), (__fp16)(dt * v1)};
            A1f[H].h2[3] = (half2_){(__fp16)(dt * v2), (__fp16)0.0f};
        } else {
#pragma unroll
            for (int pp = 0; pp < 4; ++pp) {
                A1h[H].h2[pp] = (half2_)(__fp16)0.0f;
                A1f[H].h2[pp] = (half2_)(__fp16)0.0f;
            }
        }
    }

    // Layer2 A-frags: A2[H][m][k] = w2[k*32 + sig(16H+m)], k=quad*8+j (all live)
    F A2[2];
    float4_ Cb[2];
#pragma unroll
    for (int H = 0; H < 2; ++H) {
        int u = sig(16 * H + col16);
#pragma unroll
        for (int pp = 0; pp < 4; ++pp) {
            int kk = quad * 8 + 2 * pp;
            A2[H].h2[pp] = (half2_){(__fp16)w2[kk * 32 + u], (__fp16)w2[(kk + 1) * 32 + u]};
        }
#pragma unroll
        for (int r = 0; r < 4; ++r)
            Cb[H][r] = b2[sig(16 * H + quad * 4 + r)];
    }

    // Layer3 A-frag: rows with (m&3)<3 carry w3 column (m&3); K=32 all live.
    F A3;
    {
        const int  d    = col16 & 3;
        const bool live = d < 3;
#pragma unroll
        for (int pp = 0; pp < 4; ++pp) {
            int kk = quad * 8 + 2 * pp;
            A3.h2[pp] = live
                ? (half2_){(__fp16)w3[kk * 3 + d], (__fp16)w3[(kk + 1) * 3 + d]}
                : (half2_)(__fp16)0.0f;
        }
    }
    // Layer3 C-frag: b3 folded (row = quad*4+reg; reg<3 = k_d for every quad)
    float4_ C3;
#pragma unroll
    for (int r = 0; r < 4; ++r)
        C3[r] = (r < 3) ? b3[r] : 0.0f;

    // zero C-frag for layer1
    float4_ Zc;
#pragma unroll
    for (int r = 0; r < 4; ++r) Zc[r] = 0.0f;

    int sidx[8];
    unsigned long long smask = 0ull;
#pragma unroll
    for (int j = 0; j < 8; ++j) {
        int id = (int)rintf(samples[j] / dt) - 1;   // jnp.round = RNE
        id = id < 0 ? 0 : (id > NSTEPS - 1 ? NSTEPS - 1 : id);
        id = __builtin_amdgcn_readfirstlane(id);    // wave-uniform -> SGPR
        sidx[j] = id;
        smask |= 1ull << id;
    }
    const float wo0 = w_out[0], wo1 = w_out[1], wo2 = w_out[2];
    const float bo  = b_out[0];

    float y0 = x[(size_t)row * 3 + 0];
    float y1 = x[(size_t)row * 3 + 1];
    float y2 = x[(size_t)row * 3 + 2];

    const half2_ zh = (half2_)(__fp16)0.0f;

#pragma unroll 1
    for (int s = 0; s < NSTEPS; ++s) {
        float acc0 = 0.f, acc1 = 0.f, acc2 = 0.f;

        // y-half2s once per STEP (layer1 y-part is stage-invariant)
        half2_ yp01 = __builtin_amdgcn_cvt_pkrtz(y0, y1);
        half2_ yp2o = __builtin_amdgcn_cvt_pkrtz(y2, 1.0f);

        float k0 = 0.f, k1 = 0.f, k2 = 0.f;   // kprev (zero at st=0)

#pragma unroll
        for (int st = 0; st < 4; ++st) {
            // ---- layer1: B = (y | 1 | kprev | 0); quads>=1 don't-care ----
            half2_ kp01 = (st == 0) ? zh : __builtin_amdgcn_cvt_pkrtz(k0, k1);
            half2_ kp2o = (st == 0) ? zh : __builtin_amdgcn_cvt_pkrtz(k2, 0.0f);
            F BL1;
            BL1.h2[0] = yp01; BL1.h2[1] = yp2o;
            BL1.h2[2] = kp01; BL1.h2[3] = kp2o;

            float4_ D1_0, D1_1;
            if (st == 3) {
                D1_0 = __builtin_amdgcn_mfma_f32_16x16x32_f16(A1f[0].h8, BL1.h8, Zc, 0, 0, 0);
                D1_1 = __builtin_amdgcn_mfma_f32_16x16x32_f16(A1f[1].h8, BL1.h8, Zc, 0, 0, 0);
            } else {
                D1_0 = __builtin_amdgcn_mfma_f32_16x16x32_f16(A1h[0].h8, BL1.h8, Zc, 0, 0, 0);
                D1_1 = __builtin_amdgcn_mfma_f32_16x16x32_f16(A1h[1].h8, BL1.h8, Zc, 0, 0, 0);
            }

            // ---- relu-pack -> layer2 B-frag (sigma makes this exact) ----
            F P;
            P.h2[0] = relu_pk_f16(D1_0[0], D1_0[1]);
            P.h2[1] = relu_pk_f16(D1_0[2], D1_0[3]);
            P.h2[2] = relu_pk_f16(D1_1[0], D1_1[1]);
            P.h2[3] = relu_pk_f16(D1_1[2], D1_1[3]);

            // ---- layer2: two INDEPENDENT MFMAs (K=32 each) ----
            float4_ D2_0 = __builtin_amdgcn_mfma_f32_16x16x32_f16(A2[0].h8, P.h8, Cb[0], 0, 0, 0);
            float4_ D2_1 = __builtin_amdgcn_mfma_f32_16x16x32_f16(A2[1].h8, P.h8, Cb[1], 0, 0, 0);

            // ---- relu-pack -> layer3 B-frag ----
            F Q;
            Q.h2[0] = relu_pk_f16(D2_0[0], D2_0[1]);
            Q.h2[1] = relu_pk_f16(D2_0[2], D2_0[3]);
            Q.h2[2] = relu_pk_f16(D2_1[0], D2_1[1]);
            Q.h2[3] = relu_pk_f16(D2_1[2], D2_1[3]);

            // ---- layer3: ONE MFMA; dup rows -> k in every quad's regs 0..2 ----
            float4_ D3 = __builtin_amdgcn_mfma_f32_16x16x32_f16(A3.h8, Q.h8, C3, 0, 0, 0);

            k0 = D3[0];
            k1 = D3[1];
            k2 = D3[2];

            const float ca = (st == 1 || st == 2) ? 2.0f : 1.0f;
            acc0 = fmaf(ca, k0, acc0); acc1 = fmaf(ca, k1, acc1); acc2 = fmaf(ca, k2, acc2);
        }
        y0 = fmaf(dt6, acc0, y0); y1 = fmaf(dt6, acc1, y1); y2 = fmaf(dt6, acc2, y2);

        // wave-uniform SALU fast path: most steps store nothing
        if ((smask >> s) & 1ull) {
            if (quad == 0) {
#pragma unroll
                for (int j = 0; j < 8; ++j) {
                    if (sidx[j] == s) {
                        out[(size_t)j * B + row] = fmaf(y2, wo2, fmaf(y1, wo1, fmaf(y0, wo0, bo)));
                    }
                }
            }
        }
    }
}

extern "C" void kernel_launch(void* const* d_in, const int* in_sizes, int n_in,
                              void* d_out, int out_size, void* d_ws, size_t ws_size,
                              hipStream_t stream) {
    const float* x       = (const float*)d_in[0];
    const float* samples = (const float*)d_in[1];
    const float* w1      = (const float*)d_in[2];
    const float* b1      = (const float*)d_in[3];
    const float* w2      = (const float*)d_in[4];
    const float* b2      = (const float*)d_in[5];
    const float* w3      = (const float*)d_in[6];
    const float* b3      = (const float*)d_in[7];
    const float* w_out   = (const float*)d_in[8];
    const float* b_out   = (const float*)d_in[9];
    float* out = (float*)d_out;

    const int B = in_sizes[0] / 3;           // 131072
    const int rowsPerBlock = 64;             // 4 waves x 16 samples
    const int grid = (B + rowsPerBlock - 1) / rowsPerBlock;   // 2048
    ode_rk4_mfma<<<grid, 256, 0, stream>>>(
        x, samples, w1, b1, w2, b2, w3, b3, w_out, b_out, out, B);
}

// Round 8
// 211.347 us; speedup vs baseline: 1.0180x; 1.0180x over previous
//
#include <hip/hip_runtime.h>

#define NSTEPS 64

typedef __attribute__((ext_vector_type(4)))  float  float4_;   // 16x16 MFMA C/D
typedef __attribute__((ext_vector_type(2)))  __fp16 half2_;    // packed f16
typedef __attribute__((ext_vector_type(8)))  __fp16 half8_;    // f16 MFMA A/B operand

__device__ __forceinline__ half2_ relu_pk_f16(float a, float b) {
    half2_ h = __builtin_amdgcn_cvt_pkrtz(a, b);               // v_cvt_pkrtz_f16_f32
    return __builtin_elementwise_max(h, (half2_)(__fp16)0);    // v_pk_max_f16
}

// R22 (this round): algebraic RK fusion on the 16x16x32 shape.
// Layer1 linear pre-relu + layer3 linear post-relu =>
//   h1pre(st) = (y + ci*b3)*W1 + b1 + ci*(h2prev * M),  M = W3*W1 (32x32)
//   y_new     = y + dt6*(S*W3 + 6*b3),  S = sum(ca*h2_st)  (ca = 1,2,2,1)
// Per-stage L3, k extraction, k-cvt, BL1 assembly, RK scalar fmas: GONE.
// S accumulates in PACKED f16 (v_pk_fma); one L3 MFMA per STEP.
// b3 exactness via three By variants (y | y+dt2*b3 | y+dt*b3) -> three
// base-D1 MFMA pairs per step (C-frags D1baseH/F live across stages).
// 16x16x32 layout (validated on HW by R7 passing):
//   A[m][k]: m=lane&15, k=(lane>>4)*8+j ; B same ; D[row][col]: col=lane&15,
//   row=quad*4+reg. sig(p) = ((p&15)>>2)*8 + (p&3) + (p<16?0:4).
// Q-slot identity (R7-proven): B k-slot (quad*8+j) holds h2-UNIT quad*8+j,
// so M/A3 fragments index weights by k directly.
// R7 spill lesson: (256,6) cap 85 forced scratch (WRITE 13MB). (256,4)=128.
__global__ __launch_bounds__(256, 4)
void ode_rk4_mfma(const float* __restrict__ x,
                  const float* __restrict__ samples,
                  const float* __restrict__ w1, const float* __restrict__ b1,
                  const float* __restrict__ w2, const float* __restrict__ b2,
                  const float* __restrict__ w3, const float* __restrict__ b3,
                  const float* __restrict__ w_out, const float* __restrict__ b_out,
                  float* __restrict__ out, int B)
{
    const int lane  = threadIdx.x & 63;
    const int w     = threadIdx.x >> 6;
    const int col16 = lane & 15;              // this lane's sample (mod 16)
    const int quad  = lane >> 4;              // 0..3 (k-group / row-group)

    const int rowBase = (blockIdx.x * 4 + w) * 16;
    const int row = rowBase + col16;          // sample row (4x redundant over quads)

    auto sig = [](int p) -> int {
        int q = (p & 15) >> 2, r = p & 3;
        return q * 8 + r + ((p < 16) ? 0 : 4);
    };

    // ---- scalars ----
    const float maxT = samples[7];
    const float dt   = maxT / 64.0f;
    const float dt2  = 0.5f * dt;
    const float dt6  = dt / 6.0f;

    union F { half2_ h2[4]; half8_ h8; };

    // ---- persistent MFMA operands ----
    // A1y[H]: k=0..2 = W1 rows, k=3 = b1 (B carries 1.0); quads>=1 zero.
    F A1y[2];
#pragma unroll
    for (int H = 0; H < 2; ++H) {
        if (quad == 0) {
            int u = sig(16 * H + col16);
            A1y[H].h2[0] = (half2_){(__fp16)w1[0 * 32 + u], (__fp16)w1[1 * 32 + u]};
            A1y[H].h2[1] = (half2_){(__fp16)w1[2 * 32 + u], (__fp16)b1[u]};
            A1y[H].h2[2] = (half2_)(__fp16)0.0f;
            A1y[H].h2[3] = (half2_)(__fp16)0.0f;
        } else {
#pragma unroll
            for (int pp = 0; pp < 4; ++pp) A1y[H].h2[pp] = (half2_)(__fp16)0.0f;
        }
    }

    // M = W3*W1 fragments, ci baked: Mh (dt2), Mf (dt). A[m][k] = ci*M[k][u].
    F Mh[2], Mf[2];
#pragma unroll
    for (int H = 0; H < 2; ++H) {
        int u = sig(16 * H + col16);
#pragma unroll
        for (int pp = 0; pp < 4; ++pp) {
            int kk = quad * 8 + 2 * pp;
            float m0 = w3[kk * 3 + 0] * w1[0 * 32 + u]
                     + w3[kk * 3 + 1] * w1[1 * 32 + u]
                     + w3[kk * 3 + 2] * w1[2 * 32 + u];
            float m1 = w3[(kk + 1) * 3 + 0] * w1[0 * 32 + u]
                     + w3[(kk + 1) * 3 + 1] * w1[1 * 32 + u]
                     + w3[(kk + 1) * 3 + 2] * w1[2 * 32 + u];
            Mh[H].h2[pp] = (half2_){(__fp16)(dt2 * m0), (__fp16)(dt2 * m1)};
            Mf[H].h2[pp] = (half2_){(__fp16)(dt  * m0), (__fp16)(dt  * m1)};
        }
    }

    // Layer2 A-frags + bias C-frags (R7-validated)
    F A2[2];
    float4_ Cb[2];
#pragma unroll
    for (int H = 0; H < 2; ++H) {
        int u = sig(16 * H + col16);
#pragma unroll
        for (int pp = 0; pp < 4; ++pp) {
            int kk = quad * 8 + 2 * pp;
            A2[H].h2[pp] = (half2_){(__fp16)w2[kk * 32 + u], (__fp16)w2[(kk + 1) * 32 + u]};
        }
#pragma unroll
        for (int r = 0; r < 4; ++r)
            Cb[H][r] = b2[sig(16 * H + quad * 4 + r)];
    }

    // Layer3 A-frag with row duplication (R7-validated): (m&3)<3 carry w3.
    F A3;
    {
        const int  d    = col16 & 3;
        const bool live = d < 3;
#pragma unroll
        for (int pp = 0; pp < 4; ++pp) {
            int kk = quad * 8 + 2 * pp;
            A3.h2[pp] = live
                ? (half2_){(__fp16)w3[kk * 3 + d], (__fp16)w3[(kk + 1) * 3 + d]}
                : (half2_)(__fp16)0.0f;
        }
    }
    // C3 = 6*b3 (ksum = S*W3 + 6*b3)
    float4_ C3;
#pragma unroll
    for (int r = 0; r < 4; ++r)
        C3[r] = (r < 3) ? 6.0f * b3[r] : 0.0f;

    float4_ Zc;
#pragma unroll
    for (int r = 0; r < 4; ++r) Zc[r] = 0.0f;

    int sidx[8];
    unsigned long long smask = 0ull;
#pragma unroll
    for (int j = 0; j < 8; ++j) {
        int id = (int)rintf(samples[j] / dt) - 1;   // jnp.round = RNE
        id = id < 0 ? 0 : (id > NSTEPS - 1 ? NSTEPS - 1 : id);
        id = __builtin_amdgcn_readfirstlane(id);    // wave-uniform -> SGPR
        sidx[j] = id;
        smask |= 1ull << id;
    }
    const float wo0 = w_out[0], wo1 = w_out[1], wo2 = w_out[2];
    const float bo  = b_out[0];
    // By-shift constants (SGPR): ci*b3
    const float cH0 = dt2 * b3[0], cH1 = dt2 * b3[1], cH2 = dt2 * b3[2];
    const float cF0 = dt  * b3[0], cF1 = dt  * b3[1], cF2 = dt  * b3[2];

    float y0 = x[(size_t)row * 3 + 0];
    float y1 = x[(size_t)row * 3 + 1];
    float y2 = x[(size_t)row * 3 + 2];

#pragma unroll 1
    for (int s = 0; s < NSTEPS; ++s) {
        // ---- three By variants: y | y+dt2*b3 | y+dt*b3 ----
        half2_ b0a = __builtin_amdgcn_cvt_pkrtz(y0, y1);
        half2_ b0b = __builtin_amdgcn_cvt_pkrtz(y2, 1.0f);
        half2_ bHa = __builtin_amdgcn_cvt_pkrtz(y0 + cH0, y1 + cH1);
        half2_ bHb = __builtin_amdgcn_cvt_pkrtz(y2 + cH2, 1.0f);
        half2_ bFa = __builtin_amdgcn_cvt_pkrtz(y0 + cF0, y1 + cF1);
        half2_ bFb = __builtin_amdgcn_cvt_pkrtz(y2 + cF2, 1.0f);
        F By0, ByH, ByF;
        By0.h2[0] = b0a; By0.h2[1] = b0b; By0.h2[2] = b0a; By0.h2[3] = b0b;
        ByH.h2[0] = bHa; ByH.h2[1] = bHb; ByH.h2[2] = bHa; ByH.h2[3] = bHb;
        ByF.h2[0] = bFa; ByF.h2[1] = bFb; ByF.h2[2] = bFa; ByF.h2[3] = bFb;

        // ---- base-D1 MFMAs (independent; pipe-packed at step head) ----
        float4_ D1s0_0 = __builtin_amdgcn_mfma_f32_16x16x32_f16(A1y[0].h8, By0.h8, Zc, 0, 0, 0);
        float4_ D1s0_1 = __builtin_amdgcn_mfma_f32_16x16x32_f16(A1y[1].h8, By0.h8, Zc, 0, 0, 0);
        float4_ DbH0   = __builtin_amdgcn_mfma_f32_16x16x32_f16(A1y[0].h8, ByH.h8, Zc, 0, 0, 0);
        float4_ DbH1   = __builtin_amdgcn_mfma_f32_16x16x32_f16(A1y[1].h8, ByH.h8, Zc, 0, 0, 0);
        float4_ DbF0   = __builtin_amdgcn_mfma_f32_16x16x32_f16(A1y[0].h8, ByF.h8, Zc, 0, 0, 0);
        float4_ DbF1   = __builtin_amdgcn_mfma_f32_16x16x32_f16(A1y[1].h8, ByF.h8, Zc, 0, 0, 0);

        F Q, Sacc;

        // ---- st0 ----
        {
            F P;
            P.h2[0] = relu_pk_f16(D1s0_0[0], D1s0_0[1]);
            P.h2[1] = relu_pk_f16(D1s0_0[2], D1s0_0[3]);
            P.h2[2] = relu_pk_f16(D1s0_1[0], D1s0_1[1]);
            P.h2[3] = relu_pk_f16(D1s0_1[2], D1s0_1[3]);
            float4_ D2_0 = __builtin_amdgcn_mfma_f32_16x16x32_f16(A2[0].h8, P.h8, Cb[0], 0, 0, 0);
            float4_ D2_1 = __builtin_amdgcn_mfma_f32_16x16x32_f16(A2[1].h8, P.h8, Cb[1], 0, 0, 0);
            Q.h2[0] = relu_pk_f16(D2_0[0], D2_0[1]);
            Q.h2[1] = relu_pk_f16(D2_0[2], D2_0[3]);
            Q.h2[2] = relu_pk_f16(D2_1[0], D2_1[1]);
            Q.h2[3] = relu_pk_f16(D2_1[2], D2_1[3]);
#pragma unroll
            for (int pp = 0; pp < 4; ++pp) Sacc.h2[pp] = Q.h2[pp];   // ca=1
        }

        // ---- st1..st3 ----
#pragma unroll
        for (int st = 1; st < 4; ++st) {
            float4_ D1_0, D1_1;
            if (st == 3) {
                D1_0 = __builtin_amdgcn_mfma_f32_16x16x32_f16(Mf[0].h8, Q.h8, DbF0, 0, 0, 0);
                D1_1 = __builtin_amdgcn_mfma_f32_16x16x32_f16(Mf[1].h8, Q.h8, DbF1, 0, 0, 0);
            } else {
                D1_0 = __builtin_amdgcn_mfma_f32_16x16x32_f16(Mh[0].h8, Q.h8, DbH0, 0, 0, 0);
                D1_1 = __builtin_amdgcn_mfma_f32_16x16x32_f16(Mh[1].h8, Q.h8, DbH1, 0, 0, 0);
            }
            F P;
            P.h2[0] = relu_pk_f16(D1_0[0], D1_0[1]);
            P.h2[1] = relu_pk_f16(D1_0[2], D1_0[3]);
            P.h2[2] = relu_pk_f16(D1_1[0], D1_1[1]);
            P.h2[3] = relu_pk_f16(D1_1[2], D1_1[3]);
            float4_ D2_0 = __builtin_amdgcn_mfma_f32_16x16x32_f16(A2[0].h8, P.h8, Cb[0], 0, 0, 0);
            float4_ D2_1 = __builtin_amdgcn_mfma_f32_16x16x32_f16(A2[1].h8, P.h8, Cb[1], 0, 0, 0);
            Q.h2[0] = relu_pk_f16(D2_0[0], D2_0[1]);
            Q.h2[1] = relu_pk_f16(D2_0[2], D2_0[3]);
            Q.h2[2] = relu_pk_f16(D2_1[0], D2_1[1]);
            Q.h2[3] = relu_pk_f16(D2_1[2], D2_1[3]);
            const __fp16 ca = (st == 3) ? (__fp16)1.0f : (__fp16)2.0f;
#pragma unroll
            for (int pp = 0; pp < 4; ++pp)
                Sacc.h2[pp] += ca * Q.h2[pp];                        // v_pk_fma_f16
        }

        // ---- step end: one L3 MFMA on the f16 h2-sum ----
        float4_ D3 = __builtin_amdgcn_mfma_f32_16x16x32_f16(A3.h8, Sacc.h8, C3, 0, 0, 0);
        y0 = fmaf(dt6, D3[0], y0);
        y1 = fmaf(dt6, D3[1], y1);
        y2 = fmaf(dt6, D3[2], y2);

        // wave-uniform SALU fast path: most steps store nothing
        if ((smask >> s) & 1ull) {
            if (quad == 0) {
#pragma unroll
                for (int j = 0; j < 8; ++j) {
                    if (sidx[j] == s) {
                        out[(size_t)j * B + row] = fmaf(y2, wo2, fmaf(y1, wo1, fmaf(y0, wo0, bo)));
                    }
                }
            }
        }
    }
}

extern "C" void kernel_launch(void* const* d_in, const int* in_sizes, int n_in,
                              void* d_out, int out_size, void* d_ws, size_t ws_size,
                              hipStream_t stream) {
    const float* x       = (const float*)d_in[0];
    const float* samples = (const float*)d_in[1];
    const float* w1      = (const float*)d_in[2];
    const float* b1      = (const float*)d_in[3];
    const float* w2      = (const float*)d_in[4];
    const float* b2      = (const float*)d_in[5];
    const float* w3      = (const float*)d_in[6];
    const float* b3      = (const float*)d_in[7];
    const float* w_out   = (const float*)d_in[8];
    const float* b_out   = (const float*)d_in[9];
    float* out = (float*)d_out;

    const int B = in_sizes[0] / 3;           // 131072
    const int rowsPerBlock = 64;             // 4 waves x 16 samples
    const int grid = (B + rowsPerBlock - 1) / rowsPerBlock;   // 2048
    ode_rk4_mfma<<<grid, 256, 0, stream>>>(
        x, samples, w1, b1, w2, b2, w3, b3, w_out, b_out, out, B);
}

// Round 9
// 208.909 us; speedup vs baseline: 1.0299x; 1.0117x over previous
//
#include <hip/hip_runtime.h>

#define NSTEPS 64

typedef __attribute__((ext_vector_type(4)))  float  float4_;   // 16x16 MFMA C/D
typedef __attribute__((ext_vector_type(2)))  __fp16 half2_;    // packed f16
typedef __attribute__((ext_vector_type(8)))  __fp16 half8_;    // f16 MFMA A/B operand

__device__ __forceinline__ half2_ relu_pk_f16(float a, float b) {
    half2_ h = __builtin_amdgcn_cvt_pkrtz(a, b);               // v_cvt_pkrtz_f16_f32
    return __builtin_elementwise_max(h, (half2_)(__fp16)0);    // v_pk_max_f16
}

// R23 (this round): z-space state. R2/R6/R8 counters show wall ~= VALU_busy
// + MFMA_busy (pipes barely overlap), so minimize the SUM and raise TLP.
// State: zb = y*W1 + b1 kept in f32 D-LAYOUT (position p=16H+quad*4+r holds
// unit sig(p)) -> st0's P = relu_pk(zb) DIRECTLY, no layer1 MFMA, no y-cvt.
// Exact algebra:  M = W3*W1;  c = b3*W1 (D-layout consts, ci-scaled):
//   h1pre_st = zb + ci*(h2prev*M) + ci*c          (st>=1; C-operand = zb+ci*c)
//   zb_next  = zb + dt6*(S*M) + dt*c,  S = Q0+2Q1+2Q2+Q3  (f16 pk_fma)
//   y_next   = y + dt6*(S*W3 + 6*b3)              (one L3 MFMA, R8-validated)
// st3 reuses dt2-scaled M by feeding 2*Q (f16-exact scale) -> no Mf frags.
// MFMA/step: 3x2 (M-path) + 4x2 (L2) + 1 (L3) + 2 (z-upd) = 17 (R8: 21).
// 16x16x32 layout + sig + Q-slot identity: all validated by R7/R8 passing.
// 1-wave blocks (8192) -> wave-granular residency; ~100 total regs targets
// 4-5 waves/SIMD. setprio(1) around MFMAs (independent waves, attn-like
// regime where it measured +4-7%).
__global__ __launch_bounds__(64, 4)
void ode_rk4_mfma(const float* __restrict__ x,
                  const float* __restrict__ samples,
                  const float* __restrict__ w1, const float* __restrict__ b1,
                  const float* __restrict__ w2, const float* __restrict__ b2,
                  const float* __restrict__ w3, const float* __restrict__ b3,
                  const float* __restrict__ w_out, const float* __restrict__ b_out,
                  float* __restrict__ out, int B)
{
    const int lane  = threadIdx.x & 63;
    const int col16 = lane & 15;              // this lane's sample (mod 16)
    const int quad  = lane >> 4;              // 0..3 (k-group / row-group)

    const int row = blockIdx.x * 16 + col16;  // sample row (4x redundant over quads)

    auto sig = [](int p) -> int {
        int q = (p & 15) >> 2, r = p & 3;
        return q * 8 + r + ((p < 16) ? 0 : 4);
    };

    // ---- scalars ----
    const float maxT = samples[7];
    const float dt   = maxT / 64.0f;
    const float dt2  = 0.5f * dt;
    const float dt6  = dt / 6.0f;

    union F { half2_ h2[4]; half8_ h8; };

    // ---- persistent MFMA operands ----
    // M = W3*W1 fragments: Mh (ci=dt2 baked), Mz (dt6 baked). A[m][k]=ci*M[k][u].
    F Mh[2], Mz[2];
#pragma unroll
    for (int H = 0; H < 2; ++H) {
        int u = sig(16 * H + col16);
#pragma unroll
        for (int pp = 0; pp < 4; ++pp) {
            int kk = quad * 8 + 2 * pp;
            float m0 = w3[kk * 3 + 0] * w1[0 * 32 + u]
                     + w3[kk * 3 + 1] * w1[1 * 32 + u]
                     + w3[kk * 3 + 2] * w1[2 * 32 + u];
            float m1 = w3[(kk + 1) * 3 + 0] * w1[0 * 32 + u]
                     + w3[(kk + 1) * 3 + 1] * w1[1 * 32 + u]
                     + w3[(kk + 1) * 3 + 2] * w1[2 * 32 + u];
            Mh[H].h2[pp] = (half2_){(__fp16)(dt2 * m0), (__fp16)(dt2 * m1)};
            Mz[H].h2[pp] = (half2_){(__fp16)(dt6 * m0), (__fp16)(dt6 * m1)};
        }
    }

    // Layer2 A-frags + bias C-frags (R7/R8-validated)
    F A2[2];
    float4_ Cb[2];
#pragma unroll
    for (int H = 0; H < 2; ++H) {
        int u = sig(16 * H + col16);
#pragma unroll
        for (int pp = 0; pp < 4; ++pp) {
            int kk = quad * 8 + 2 * pp;
            A2[H].h2[pp] = (half2_){(__fp16)w2[kk * 32 + u], (__fp16)w2[(kk + 1) * 32 + u]};
        }
#pragma unroll
        for (int r = 0; r < 4; ++r)
            Cb[H][r] = b2[sig(16 * H + quad * 4 + r)];
    }

    // Layer3 A-frag with row duplication (R7/R8-validated)
    F A3;
    {
        const int  d    = col16 & 3;
        const bool live = d < 3;
#pragma unroll
        for (int pp = 0; pp < 4; ++pp) {
            int kk = quad * 8 + 2 * pp;
            A3.h2[pp] = live
                ? (half2_){(__fp16)w3[kk * 3 + d], (__fp16)w3[(kk + 1) * 3 + d]}
                : (half2_)(__fp16)0.0f;
        }
    }
    float4_ C3;
#pragma unroll
    for (int r = 0; r < 4; ++r)
        C3[r] = (r < 3) ? 6.0f * b3[r] : 0.0f;

    // cH = dt2*(b3*W1) in D-layout (per-step shift constant; dt*c = 2*cH)
    float4_ cH[2];
#pragma unroll
    for (int H = 0; H < 2; ++H)
#pragma unroll
        for (int r = 0; r < 4; ++r) {
            int u = sig(16 * H + quad * 4 + r);
            cH[H][r] = dt2 * (b3[0] * w1[0 * 32 + u] + b3[1] * w1[1 * 32 + u] + b3[2] * w1[2 * 32 + u]);
        }

    int sidx[8];
    unsigned long long smask = 0ull;
#pragma unroll
    for (int j = 0; j < 8; ++j) {
        int id = (int)rintf(samples[j] / dt) - 1;   // jnp.round = RNE
        id = id < 0 ? 0 : (id > NSTEPS - 1 ? NSTEPS - 1 : id);
        id = __builtin_amdgcn_readfirstlane(id);    // wave-uniform -> SGPR
        sidx[j] = id;
        smask |= 1ull << id;
    }
    const float wo0 = w_out[0], wo1 = w_out[1], wo2 = w_out[2];
    const float bo  = b_out[0];

    float y0 = x[(size_t)row * 3 + 0];
    float y1 = x[(size_t)row * 3 + 1];
    float y2 = x[(size_t)row * 3 + 2];

    // ---- prologue: zb = y*W1 + b1 in D-layout (A1y/Zc/By die after this) ----
    float4_ zb0, zb1;
    {
        F A1y[2];
#pragma unroll
        for (int H = 0; H < 2; ++H) {
            if (quad == 0) {
                int u = sig(16 * H + col16);
                A1y[H].h2[0] = (half2_){(__fp16)w1[0 * 32 + u], (__fp16)w1[1 * 32 + u]};
                A1y[H].h2[1] = (half2_){(__fp16)w1[2 * 32 + u], (__fp16)b1[u]};
                A1y[H].h2[2] = (half2_)(__fp16)0.0f;
                A1y[H].h2[3] = (half2_)(__fp16)0.0f;
            } else {
#pragma unroll
                for (int pp = 0; pp < 4; ++pp) A1y[H].h2[pp] = (half2_)(__fp16)0.0f;
            }
        }
        float4_ Zc;
#pragma unroll
        for (int r = 0; r < 4; ++r) Zc[r] = 0.0f;
        half2_ b0a = __builtin_amdgcn_cvt_pkrtz(y0, y1);
        half2_ b0b = __builtin_amdgcn_cvt_pkrtz(y2, 1.0f);
        F By;
        By.h2[0] = b0a; By.h2[1] = b0b; By.h2[2] = b0a; By.h2[3] = b0b;
        zb0 = __builtin_amdgcn_mfma_f32_16x16x32_f16(A1y[0].h8, By.h8, Zc, 0, 0, 0);
        zb1 = __builtin_amdgcn_mfma_f32_16x16x32_f16(A1y[1].h8, By.h8, Zc, 0, 0, 0);
    }

    const half2_ two = (half2_)(__fp16)2.0f;

#pragma unroll 1
    for (int s = 0; s < NSTEPS; ++s) {
        F P, Q, S;

        // ---- st0: P directly from zb (no MFMA, no cvt of y) ----
        P.h2[0] = relu_pk_f16(zb0[0], zb0[1]);
        P.h2[1] = relu_pk_f16(zb0[2], zb0[3]);
        P.h2[2] = relu_pk_f16(zb1[0], zb1[1]);
        P.h2[3] = relu_pk_f16(zb1[2], zb1[3]);
        __builtin_amdgcn_s_setprio(1);
        float4_ D2_0 = __builtin_amdgcn_mfma_f32_16x16x32_f16(A2[0].h8, P.h8, Cb[0], 0, 0, 0);
        float4_ D2_1 = __builtin_amdgcn_mfma_f32_16x16x32_f16(A2[1].h8, P.h8, Cb[1], 0, 0, 0);
        __builtin_amdgcn_s_setprio(0);
        Q.h2[0] = relu_pk_f16(D2_0[0], D2_0[1]);
        Q.h2[1] = relu_pk_f16(D2_0[2], D2_0[3]);
        Q.h2[2] = relu_pk_f16(D2_1[0], D2_1[1]);
        Q.h2[3] = relu_pk_f16(D2_1[2], D2_1[3]);
#pragma unroll
        for (int pp = 0; pp < 4; ++pp) S.h2[pp] = Q.h2[pp];      // ca=1

        // shifted C for st1/st2: zb + cH
        float4_ zh0 = zb0 + cH[0];
        float4_ zh1 = zb1 + cH[1];

        // ---- st1, st2 (ca=2) ----
#pragma unroll
        for (int st = 1; st <= 2; ++st) {
            __builtin_amdgcn_s_setprio(1);
            float4_ D1_0 = __builtin_amdgcn_mfma_f32_16x16x32_f16(Mh[0].h8, Q.h8, zh0, 0, 0, 0);
            float4_ D1_1 = __builtin_amdgcn_mfma_f32_16x16x32_f16(Mh[1].h8, Q.h8, zh1, 0, 0, 0);
            __builtin_amdgcn_s_setprio(0);
            P.h2[0] = relu_pk_f16(D1_0[0], D1_0[1]);
            P.h2[1] = relu_pk_f16(D1_0[2], D1_0[3]);
            P.h2[2] = relu_pk_f16(D1_1[0], D1_1[1]);
            P.h2[3] = relu_pk_f16(D1_1[2], D1_1[3]);
            __builtin_amdgcn_s_setprio(1);
            float4_ E0 = __builtin_amdgcn_mfma_f32_16x16x32_f16(A2[0].h8, P.h8, Cb[0], 0, 0, 0);
            float4_ E1 = __builtin_amdgcn_mfma_f32_16x16x32_f16(A2[1].h8, P.h8, Cb[1], 0, 0, 0);
            __builtin_amdgcn_s_setprio(0);
            Q.h2[0] = relu_pk_f16(E0[0], E0[1]);
            Q.h2[1] = relu_pk_f16(E0[2], E0[3]);
            Q.h2[2] = relu_pk_f16(E1[0], E1[1]);
            Q.h2[3] = relu_pk_f16(E1[2], E1[3]);
#pragma unroll
            for (int pp = 0; pp < 4; ++pp)
                S.h2[pp] += two * Q.h2[pp];                      // v_pk_fma_f16
        }

        // ---- st3 (ca=1): C = zb + 2*cH; feed 2*Q into dt2-scaled M ----
        zh0 = zh0 + cH[0];
        zh1 = zh1 + cH[1];
        F Qd;
#pragma unroll
        for (int pp = 0; pp < 4; ++pp) Qd.h2[pp] = Q.h2[pp] + Q.h2[pp];  // exact x2
        __builtin_amdgcn_s_setprio(1);
        float4_ D1_0 = __builtin_amdgcn_mfma_f32_16x16x32_f16(Mh[0].h8, Qd.h8, zh0, 0, 0, 0);
        float4_ D1_1 = __builtin_amdgcn_mfma_f32_16x16x32_f16(Mh[1].h8, Qd.h8, zh1, 0, 0, 0);
        __builtin_amdgcn_s_setprio(0);
        P.h2[0] = relu_pk_f16(D1_0[0], D1_0[1]);
        P.h2[1] = relu_pk_f16(D1_0[2], D1_0[3]);
        P.h2[2] = relu_pk_f16(D1_1[0], D1_1[1]);
        P.h2[3] = relu_pk_f16(D1_1[2], D1_1[3]);
        __builtin_amdgcn_s_setprio(1);
        float4_ E0 = __builtin_amdgcn_mfma_f32_16x16x32_f16(A2[0].h8, P.h8, Cb[0], 0, 0, 0);
        float4_ E1 = __builtin_amdgcn_mfma_f32_16x16x32_f16(A2[1].h8, P.h8, Cb[1], 0, 0, 0);
        __builtin_amdgcn_s_setprio(0);
        Q.h2[0] = relu_pk_f16(E0[0], E0[1]);
        Q.h2[1] = relu_pk_f16(E0[2], E0[3]);
        Q.h2[2] = relu_pk_f16(E1[0], E1[1]);
        Q.h2[3] = relu_pk_f16(E1[2], E1[3]);
#pragma unroll
        for (int pp = 0; pp < 4; ++pp) S.h2[pp] += Q.h2[pp];     // ca=1

        // ---- y-update: one L3 MFMA on S ----
        __builtin_amdgcn_s_setprio(1);
        float4_ D3 = __builtin_amdgcn_mfma_f32_16x16x32_f16(A3.h8, S.h8, C3, 0, 0, 0);
        // ---- z-update: zb += dt6*(S*M) + dt*c  (C-operand carries zb) ----
        zb0 = __builtin_amdgcn_mfma_f32_16x16x32_f16(Mz[0].h8, S.h8, zb0, 0, 0, 0);
        zb1 = __builtin_amdgcn_mfma_f32_16x16x32_f16(Mz[1].h8, S.h8, zb1, 0, 0, 0);
        __builtin_amdgcn_s_setprio(0);
#pragma unroll
        for (int r = 0; r < 4; ++r) {
            zb0[r] = fmaf(2.0f, cH[0][r], zb0[r]);
            zb1[r] = fmaf(2.0f, cH[1][r], zb1[r]);
        }
        y0 = fmaf(dt6, D3[0], y0);
        y1 = fmaf(dt6, D3[1], y1);
        y2 = fmaf(dt6, D3[2], y2);

        // wave-uniform SALU fast path: most steps store nothing
        if ((smask >> s) & 1ull) {
            if (quad == 0) {
#pragma unroll
                for (int j = 0; j < 8; ++j) {
                    if (sidx[j] == s) {
                        out[(size_t)j * B + row] = fmaf(y2, wo2, fmaf(y1, wo1, fmaf(y0, wo0, bo)));
                    }
                }
            }
        }
    }
}

extern "C" void kernel_launch(void* const* d_in, const int* in_sizes, int n_in,
                              void* d_out, int out_size, void* d_ws, size_t ws_size,
                              hipStream_t stream) {
    const float* x       = (const float*)d_in[0];
    const float* samples = (const float*)d_in[1];
    const float* w1      = (const float*)d_in[2];
    const float* b1      = (const float*)d_in[3];
    const float* w2      = (const float*)d_in[4];
    const float* b2      = (const float*)d_in[5];
    const float* w3      = (const float*)d_in[6];
    const float* b3      = (const float*)d_in[7];
    const float* w_out   = (const float*)d_in[8];
    const float* b_out   = (const float*)d_in[9];
    float* out = (float*)d_out;

    const int B = in_sizes[0] / 3;           // 131072
    const int rowsPerBlock = 16;             // 1 wave x 16 samples
    const int grid = (B + rowsPerBlock - 1) / rowsPerBlock;   // 8192
    ode_rk4_mfma<<<grid, 64, 0, stream>>>(
        x, samples, w1, b1, w2, b2, w3, b3, w_out, b_out, out, B);
}